// Round 8
// baseline (957.871 us; speedup 1.0000x reference)
//
#include <hip/hip_runtime.h>
#include <math.h>

// R14: fused 2-way K-split — grid 2048, 8 stages/block, atomic last-arriver
// combine (no epilogue kernel, no draining pipeline).
// Evidence driving this:
//  - R13: CPSG=8 spilled B[8][4] (128 VGPR) to scratch -> 441 MB HBM traffic
//    at 2.07 TB/s. Stage must stay CPSG=4. (Also proves >2 TB/s is reachable.)
//  - Ladder: only block concurrency + per-block chain length ever moved time:
//    R7 (8 w/CU, 64 chunks) 149us; R11 (16 w/CU, 64 chunks) 103us;
//    R6 (16 w/CU, 32 chunks, K-split) 79.6us despite draining barriers.
//    Intra-block scheduling (R9/R10) was null.
// R14 = R11's verified stage code, byte-identical numerics, with:
//  - KS=2 inside the fused kernel: block = (token-group g, kseg ks);
//    grid 2048 -> ~6-8 blocks/CU; per-block chain halves to 8 stages.
//  - combine via d_ws: both blocks write their fp32 fold slice (8 KB),
//    __threadfence(), atomicAdd(flag[g]); second arriver reads partner
//    slice, f64-combines (f64 add exactly commutative -> order-free),
//    runs the verbatim epilogue. First arriver exits. No spinning.
//  - flags zeroed by prep_w (stream-ordered before router; graph-replay safe).
// d_ws layout: zpart 16 MB @0, wt3 1 MB @16M, flags 4 KB @17M.

typedef _Float16 f16x8 __attribute__((ext_vector_type(8)));
typedef _Float16 f16x4 __attribute__((ext_vector_type(4)));
typedef float f32x4 __attribute__((ext_vector_type(4)));

constexpr int ND = 2048, NE = 64, NK = 8, NTOK = 16384;
constexpr int KC   = 32;            // k per chunk (one MFMA K)
constexpr int CPSG = 4;             // chunks per stage (proven; CPSG=8 spills)
constexpr int NSTG = 8;             // stages per block (32 chunks = one kseg)
constexpr int MTOK = 16;            // tokens per block
constexpr int NGRP = NTOK / MTOK;   // 1024 token groups
constexpr int ZROW = 132;           // padded fp32 LDS row for epilogue
constexpr int STG_F16 = CPSG * MTOK * 64;   // 4096 f16 = 8 KB per buffer

// ---- prep: W1|W2 -> f16 hi / lo*2^11 planes in MFMA B-fragment order
// (unchanged) + zero the combine flags (runs before router, stream-ordered).
__global__ void prep_w(const float* __restrict__ W1, const float* __restrict__ W2,
                       _Float16* __restrict__ wt3, int* __restrict__ flags) {
    if (blockIdx.x == 0) {
        for (int t = threadIdx.x; t < NGRP; t += 256) flags[t] = 0;
    }
    const int g    = blockIdx.x * 256 + threadIdx.x;   // 0..32767
    const int cg   = g >> 9;
    const int rem  = g & 511;
    const int t    = rem >> 6;
    const int lane = rem & 63;
    const int col  = lane & 15, q = lane >> 4;
    const int n    = t * 16 + col;
    const float* W = (t < 4) ? W1 : W2;
    const int cn   = n & 63;
    _Float16 h[8], l[8];
    #pragma unroll
    for (int j = 0; j < 8; ++j) {
        const float v = W[(size_t)(cg * 32 + q * 8 + j) * 64 + cn];
        const _Float16 hh = (_Float16)v;
        h[j] = hh;
        l[j] = (_Float16)((v - (float)hh) * 2048.0f);
    }
    *(f16x8*)&wt3[((size_t)(cg * 2 + 0) * 8 + t) * 512 + lane * 8] = *(f16x8*)h;
    *(f16x8*)&wt3[((size_t)(cg * 2 + 1) * 8 + t) * 512 + lane * 8] = *(f16x8*)l;
}

__device__ __forceinline__ void split4(const float4 v, f16x4& hh, f16x4& ll) {
    const _Float16 h0 = (_Float16)v.x, h1 = (_Float16)v.y,
                   h2 = (_Float16)v.z, h3 = (_Float16)v.w;
    hh = (f16x4){h0, h1, h2, h3};
    ll = (f16x4){(_Float16)((v.x - (float)h0) * 2048.0f),
                 (_Float16)((v.y - (float)h1) * 2048.0f),
                 (_Float16)((v.z - (float)h2) * 2048.0f),
                 (_Float16)((v.w - (float)h3) * 2048.0f)};
}

// non-draining block barrier: LDS ordering only; vmcnt stays counted.
__device__ __forceinline__ void block_sync_lds() {
    asm volatile("s_waitcnt lgkmcnt(0)" ::: "memory");
    __builtin_amdgcn_s_barrier();
}

__global__ __launch_bounds__(256, 6)
void router_fused(const float* __restrict__ x, const _Float16* __restrict__ wt3,
                  const float* __restrict__ noise,
                  const float* __restrict__ b1, const float* __restrict__ b2,
                  float* __restrict__ zpart, int* __restrict__ flags,
                  float* __restrict__ out_sparse, float* __restrict__ out_idx,
                  float* __restrict__ out_full) {
    __shared__ __align__(16) _Float16 stage[2][STG_F16];   // 16 KB total
    __shared__ int sflag;
    const int tid  = threadIdx.x;
    const int lane = tid & 63;
    const int wu   = __builtin_amdgcn_readfirstlane(tid >> 6);
    const int col  = lane & 15, q = lane >> 4;   // col = token 0..15
    const int grp  = blockIdx.x >> 1;            // token group 0..1023
    const int ks   = blockIdx.x & 1;             // k segment (chunks ks*32..+31)
    const long tok0 = (long)grp * MTOK;
    const int ta = 2 * wu, tb = 2 * wu + 1;      // this wave's N-tiles

    // staging map (verbatim R11): 16 threads/token; thread's j-th float4
    // (j=0,1) covers chunk cc = j*2 + (fsub>>3), k-group = fsub&7.
    const int stok = tid >> 4, fsub = tid & 15;
    const float* xs = x + (tok0 + stok) * (size_t)ND + (size_t)ks * 1024 + fsub * 4;
    const int g8 = fsub & 7;
    const int wS = g8 >> 1, wh = g8 & 1;

    const _Float16* wla = wt3 + (size_t)ta * 512 + (size_t)lane * 8;
    const _Float16* wlb = wt3 + (size_t)tb * 512 + (size_t)lane * 8;

    f32x4 a0[2], a1[2];
    #pragma unroll
    for (int i = 0; i < 2; ++i)
        #pragma unroll
        for (int r = 0; r < 4; ++r) { a0[i][r] = 0.f; a1[i][r] = 0.f; }

    auto loadX = [&](float4 (&xr)[2], const int s) {
        #pragma unroll
        for (int j = 0; j < 2; ++j)
            xr[j] = *(const float4*)(xs + (size_t)s * 128 + (size_t)j * 64);
    };
    auto deposit = [&](_Float16* wb, const float4 (&xr)[2]) {
        #pragma unroll
        for (int j = 0; j < 2; ++j) {
            const int cc = j * 2 + (fsub >> 3);
            f16x4 hv, lv; split4(xr[j], hv, lv);
            const int idx = ((cc * MTOK + stok) << 6)
                          + (((wS ^ (stok & 7) ^ ((cc & 1) << 2)) << 3) + (wh << 2));
            *(f16x4*)&wb[idx]      = hv;
            *(f16x4*)&wb[idx ^ 32] = lv;
        }
    };

    // one stage (verbatim R11 structure): B JIT, x(s+1), 4 chunks x 6 MFMA,
    // deposit, non-draining barrier. Chunk index offset by ks*32.
    auto do_stage = [&](const int s, const _Float16* rb, _Float16* wb) {
        f16x8 B[CPSG][4];
        #pragma unroll
        for (int cc = 0; cc < CPSG; ++cc) {
            const size_t cb = (size_t)((ks * 32 + s * CPSG + cc)) * 8192;
            B[cc][0] = *(const f16x8*)(wla + cb);
            B[cc][1] = *(const f16x8*)(wlb + cb);
            B[cc][2] = *(const f16x8*)(wla + cb + 4096);
            B[cc][3] = *(const f16x8*)(wlb + cb + 4096);
        }
        float4 xl[2];
        if (s + 1 < NSTG) loadX(xl, s + 1);
        #pragma unroll
        for (int cc = 0; cc < CPSG; ++cc) {
            const int swz = (cc & 1) << 2;
            const int ridx = ((cc * MTOK + col) << 6)
                           + ((q ^ (col & 7) ^ swz) << 3);
            const f16x8 ah = *(const f16x8*)&rb[ridx];
            const f16x8 al = *(const f16x8*)&rb[ridx ^ 32];
            // per-accumulator chain order identical to R6..R11
            a0[0] = __builtin_amdgcn_mfma_f32_16x16x32_f16(ah, B[cc][0], a0[0], 0, 0, 0);
            a0[1] = __builtin_amdgcn_mfma_f32_16x16x32_f16(ah, B[cc][1], a0[1], 0, 0, 0);
            a1[0] = __builtin_amdgcn_mfma_f32_16x16x32_f16(ah, B[cc][2], a1[0], 0, 0, 0);
            a1[1] = __builtin_amdgcn_mfma_f32_16x16x32_f16(ah, B[cc][3], a1[1], 0, 0, 0);
            a1[0] = __builtin_amdgcn_mfma_f32_16x16x32_f16(al, B[cc][0], a1[0], 0, 0, 0);
            a1[1] = __builtin_amdgcn_mfma_f32_16x16x32_f16(al, B[cc][1], a1[1], 0, 0, 0);
        }
        if (s + 1 < NSTG) deposit(wb, xl);
        block_sync_lds();
    };

    // prologue: stage-0 deposit
    {
        float4 x0[2];
        loadX(x0, 0);
        deposit(stage[0], x0);
    }
    block_sync_lds();

    for (int sp = 0; sp < NSTG; sp += 2) {
        do_stage(sp,     stage[0], stage[1]);
        do_stage(sp + 1, stage[1], stage[0]);
    }

    // fold this kseg (identical to R6's per-seg fold) and publish the slice.
    f32x4 zk[2];
    #pragma unroll
    for (int i = 0; i < 2; ++i)
        zk[i] = a0[i] + a1[i] * 4.8828125e-4f;

    float* myslot = zpart + ((size_t)(grp * 2 + ks)) * (MTOK * 128);
    #pragma unroll
    for (int i = 0; i < 2; ++i) {
        const int n = (ta + i) * 16 + col;
        #pragma unroll
        for (int r = 0; r < 4; ++r)
            myslot[(q * 4 + r) * 128 + n] = zk[i][r];
    }
    __threadfence();
    __syncthreads();
    if (tid == 0) sflag = atomicAdd(&flags[grp], 1);
    __syncthreads();
    if (sflag == 0) return;          // first arriver: partner will combine
    __threadfence();                 // acquire side

    // second arriver: read partner slice, f64-combine (commutative), stage z.
    const float* pslot = zpart + ((size_t)(grp * 2 + (1 - ks))) * (MTOK * 128);
    float* zs = (float*)&stage[0][0];   // 16*132*4 = 8448 B <= 16 KB
    #pragma unroll
    for (int i = 0; i < 2; ++i) {
        const int n = (ta + i) * 16 + col;
        #pragma unroll
        for (int r = 0; r < 4; ++r) {
            const float pv = pslot[(q * 4 + r) * 128 + n];
            const float comb = (float)((double)zk[i][r] + (double)pv);
            zs[(q * 4 + r) * ZROW + n] = comb;
        }
    }
    __syncthreads();

    // ---- epilogue: softplus, softmax/top8/masked softmax (verbatim; 4 tok/wave).
    const float b1v = b1[lane];
    const float b2v = b2[lane];
    for (int tt = 0; tt < 4; ++tt) {
        const int lt = wu * 4 + tt;
        const long tok = tok0 + lt;
        const float z1 = zs[lt * ZROW + lane] + b1v;
        const float z2 = zs[lt * ZROW + 64 + lane] + b2v;
        const float sc = (float)log1p(exp((double)z2));   // f64 softplus
        const float nz = noise[tok * NE + lane];
        const float mixed = z1 + nz * sc;

        float vmax = mixed;
        for (int off = 32; off; off >>= 1) vmax = fmaxf(vmax, __shfl_xor(vmax, off));
        const float e = expf(mixed - vmax);
        float denom = e;
        for (int off = 32; off; off >>= 1) denom += __shfl_xor(denom, off);
        const float fullv = e / denom;

        float cur = mixed;
        int   sel = 0;
        float myidxf = 0.0f;
        #pragma unroll
        for (int r = 0; r < NK; ++r) {
            float bv = cur; int bi = lane;
            for (int off = 32; off; off >>= 1) {
                const float ov = __shfl_xor(bv, off);
                const int   oi = __shfl_xor(bi, off);
                if (ov > bv || (ov == bv && oi < bi)) { bv = ov; bi = oi; }
            }
            if (lane == r)  myidxf = (float)bi;
            if (lane == bi) { sel = 1; cur = -INFINITY; }
        }

        const float es = sel ? e : 0.0f;
        float dsum = es;
        for (int off = 32; off; off >>= 1) dsum += __shfl_xor(dsum, off);
        const float sparsev = sel ? (e / dsum) : 0.0f;

        out_full[tok * NE + lane]   = fullv;
        out_sparse[tok * NE + lane] = sparsev;
        if (lane < NK) out_idx[tok * NK + lane] = myidxf;
    }
}

extern "C" void kernel_launch(void* const* d_in, const int* in_sizes, int n_in,
                              void* d_out, int out_size, void* d_ws, size_t ws_size,
                              hipStream_t stream) {
    const float* x     = (const float*)d_in[0];
    const float* noise = (const float*)d_in[1];
    const float* W1    = (const float*)d_in[2];
    const float* b1    = (const float*)d_in[3];
    const float* W2    = (const float*)d_in[4];
    const float* b2    = (const float*)d_in[5];

    float* out_sparse = (float*)d_out;                      // [16384*64]
    float* out_idx    = out_sparse + (size_t)NTOK * NE;     // [16384*8]
    float* out_full   = out_idx + (size_t)NTOK * NK;        // [16384*64]

    float*    zpart = (float*)d_ws;                               // 16 MB slices
    _Float16* wt3   = (_Float16*)((char*)d_ws + ((size_t)16 << 20));   // 1 MB
    int*      flags = (int*)((char*)d_ws + ((size_t)17 << 20));        // 4 KB

    prep_w<<<128, 256, 0, stream>>>(W1, W2, wt3, flags);
    router_fused<<<NGRP * 2, 256, 0, stream>>>(x, wt3, noise, b1, b2,
                                               zpart, flags,
                                               out_sparse, out_idx, out_full);  // 2048 blocks
}